// Round 1
// 483.449 us; speedup vs baseline: 1.1171x; 1.1171x over previous
//
#include <hip/hip_runtime.h>
#include <hip/hip_bf16.h>

#define NN 131072
#define NE 2097152
#define FIN 32
#define HID 64
#define GFC 16
#define NG 1024
#define EPS 1e-5f
#define BCAP 10240   // per-bucket bin capacity (mean 8192, +22 sigma)

typedef __hip_bfloat16 bf16;

__device__ __forceinline__ float b2f(bf16 v) { return __bfloat162float(v); }
__device__ __forceinline__ bf16 f2b(float v) { return __float2bfloat16(v); }
__device__ __forceinline__ void rG_err(int* err, int code) { atomicCAS(err, 0, code); }

// accumulate 8 bf16 (as uint4) * mask into acc[8]
__device__ __forceinline__ void rG_acc8(float* acc, uint4 a, float m) {
    const unsigned* u = (const unsigned*)&a;
#pragma unroll
    for (int q = 0; q < 4; q++) {
        float f0 = __uint_as_float(u[q] << 16);
        float f1 = __uint_as_float(u[q] & 0xFFFF0000u);
        acc[2 * q] += f0 * m;
        acc[2 * q + 1] += f1 * m;
    }
}

// accumulate 8 bf16 (as uint4) into acc[8], no mask
__device__ __forceinline__ void rG_add8(float* acc, uint4 a) {
    const unsigned* u = (const unsigned*)&a;
#pragma unroll
    for (int q = 0; q < 4; q++) {
        acc[2 * q]     += __uint_as_float(u[q] << 16);
        acc[2 * q + 1] += __uint_as_float(u[q] & 0xFFFF0000u);
    }
}

// ---------- broadcast diagnostic code (f32 output) ----------
__global__ void rG_code(float code, float* out) {
    int i = blockIdx.x * blockDim.x + threadIdx.x;
    if (i < 2048) out[i] = code;
}

// ---------- batch histogram ----------
__global__ void rG_bhist(const int* batch, int* graph_cnt, int* err) {
    int n = blockIdx.x * blockDim.x + threadIdx.x;
    if (n < NN) {
        int bg = batch[n];
        if ((unsigned)bg >= NG) rG_err(err, 3100);
        else atomicAdd(&graph_cnt[bg], 1);
    }
}

// ---------- bin edges into 256 coarse buckets (dst>>9); no node_cnt ----------
__global__ __launch_bounds__(256) void rG_bin(const int* ei, unsigned* bin, int* bin_cnt,
                                              int* err) {
    __shared__ int h[256];
    __shared__ int base[256];
    int t = threadIdx.x;
    h[t] = 0;
    __syncthreads();
    int start = blockIdx.x * 8192;
    unsigned vals[32];
    unsigned char bks[32];
#pragma unroll
    for (int i = 0; i < 32; i++) {
        int e = start + i * 256 + t;
        int s = ei[e];
        int d = ei[NE + e];
        if ((unsigned)s >= NN || (unsigned)d >= NN) { rG_err(err, 3000); s = 0; d = 0; }
        int b = d >> 9;
        vals[i] = ((unsigned)(d & 511) << 17) | (unsigned)s;
        bks[i] = (unsigned char)b;
        atomicAdd(&h[b], 1);
    }
    __syncthreads();
    base[t] = atomicAdd(&bin_cnt[t], h[t]);
    __syncthreads();
    h[t] = 0;
    __syncthreads();
#pragma unroll
    for (int i = 0; i < 32; i++) {
        int b = bks[i];
        int r = atomicAdd(&h[b], 1);
        int p = base[b] + r;
        if (p >= BCAP) { rG_err(err, 3800); continue; }
        bin[b * BCAP + p] = vals[i];
    }
}

// ---------- scan 256 bucket counts -> bucket_base[257]; row_ptr[NN] ----------
__global__ void rG_bscan(const int* bin_cnt, int* bucket_base, int* row_ptr, int* err) {
    __shared__ int sh[256];
    int t = threadIdx.x;
    int v = bin_cnt[t];
    sh[t] = v;
    __syncthreads();
    for (int off = 1; off < 256; off <<= 1) {
        int u = (t >= off) ? sh[t - off] : 0;
        __syncthreads();
        sh[t] += u;
        __syncthreads();
    }
    bucket_base[t] = sh[t] - v;  // exclusive
    if (t == 255) {
        bucket_base[256] = sh[255];
        row_ptr[NN] = sh[255];
        if (sh[255] != NE) rG_err(err, 2000);
    }
}

// ---------- per-bucket: count 512 locals, scan -> row_ptr+dinv, scatter ------
__global__ __launch_bounds__(256) void rG_sort(const unsigned* bin, const int* bin_cnt,
                                               const int* bucket_base,
                                               int* row_ptr, float* dinv, int* col_src) {
    __shared__ int cnt[512];
    __shared__ int sA[512];
    __shared__ int sB[512];
    int t = threadIdx.x;
    int b = blockIdx.x;
    for (int i = t; i < 512; i += 256) cnt[i] = 0;
    __syncthreads();
    int m = bin_cnt[b];
    if (m > BCAP) m = BCAP;
    // pass 1: count dst-locals
    for (int j = t; j < m; j += 256) {
        int dl = bin[b * BCAP + j] >> 17;
        atomicAdd(&cnt[dl], 1);
    }
    __syncthreads();
    // inclusive scan of cnt into ping-pong buffers
    for (int i = t; i < 512; i += 256) sA[i] = cnt[i];
    __syncthreads();
    int* src = sA;
    int* dst = sB;
    for (int off = 1; off < 512; off <<= 1) {
        for (int i = t; i < 512; i += 256)
            dst[i] = src[i] + ((i >= off) ? src[i - off] : 0);
        __syncthreads();
        int* tmp = src; src = dst; dst = tmp;
    }
    // src = inclusive scan; bas[i] = bucket_base[b] + src[i] - cnt[i]
    int gbase = bucket_base[b];
    for (int i = t; i < 512; i += 256) {
        int bas = gbase + src[i] - cnt[i];
        dst[i] = bas;                       // dst buffer now holds bases
        row_ptr[b * 512 + i] = bas;
        dinv[b * 512 + i] = rsqrtf((float)cnt[i] + 1.0f);
    }
    __syncthreads();
    for (int i = t; i < 512; i += 256) cnt[i] = 0;  // reuse as cursor
    __syncthreads();
    // pass 2: scatter
    for (int j = t; j < m; j += 256) {
        unsigned v = bin[b * BCAP + j];
        int dl = v >> 17;
        int s = (int)(v & 0x1FFFFu);
        int r = atomicAdd(&cnt[dl], 1);
        col_src[dst[dl] + r] = s;
    }
}

// ---------- scan graph counts ----------
__global__ void rG_scan_graphs(const int* cnt, int* ptr, int* err) {
    __shared__ int part[1024];
    int t = threadIdx.x;
    int s = cnt[t];
    part[t] = s;
    __syncthreads();
    for (int off = 1; off < 1024; off <<= 1) {
        int v = (t >= off) ? part[t - off] : 0;
        __syncthreads();
        part[t] += v;
        __syncthreads();
    }
    ptr[t] = part[t] - s;
    if (t == 1023) {
        ptr[1024] = part[1023];
        if (part[1023] != NN) rG_err(err, 2500);
    }
}

// ---------- y = (x @ W1) * dinv (bf16 staging) ----------
__global__ __launch_bounds__(256) void rG_xw1(const float* x, const float* W1,
                                              const float* dinv, bf16* y) {
    __shared__ float ws[FIN * HID];
    __shared__ float xs[64 * (FIN + 1)];
    int t = threadIdx.x;
    for (int i = t; i < FIN * HID; i += 256) ws[i] = W1[i];
    int nb = blockIdx.x * 64;
    for (int i = t; i < 64 * FIN; i += 256) {
        int n = i / FIN, k = i % FIN;
        xs[n * (FIN + 1) + k] = x[nb * FIN + i];
    }
    __syncthreads();
    int node = t >> 2, fg = t & 3;
    float acc[16];
    for (int j = 0; j < 16; j++) acc[j] = 0.f;
    for (int k = 0; k < FIN; k++) {
        float xv = xs[node * (FIN + 1) + k];
        for (int j = 0; j < 16; j++) acc[j] += xv * ws[k * HID + fg * 16 + j];
    }
    int n = nb + node;
    float dv = dinv[n];
    for (int j = 0; j < 16; j++) y[n * HID + fg * 16 + j] = f2b(acc[j] * dv);
}

// ---------- CSR aggregation: 8 nodes/wave, 8-deep gather pipeline ----------
// lane = ns*8 + c : ns = node slot (8 consecutive nodes per wave),
//                   c  = 16B feature chunk (8 bf16).
// Each lane owns acc[8] for (node ns, features c*8..c*8+7) -> no per-edge
// shuffle reduce; epilogue (self-loop, scale, pack, store, stats) runs on all
// 64 lanes with fully coalesced 1KB/wave loads+stores.
__global__ __launch_bounds__(256) void rG_agg(const int* row_ptr, const int* col_src,
                                              const float* dinv, const float* bias,
                                              const bf16* y, bf16* outb, float* stats) {
    int t = threadIdx.x;
    int lane = t & 63, wave = t >> 6;
    int ns = lane >> 3;
    int c = lane & 7;
    float bl[8];
#pragma unroll
    for (int k = 0; k < 8; k++) bl[k] = bias[c * 8 + k];
    float ssum[8], ssq[8];
#pragma unroll
    for (int k = 0; k < 8; k++) { ssum[k] = 0.f; ssq[k] = 0.f; }
    int gw = blockIdx.x * 4 + wave;
    int nw = gridDim.x * 4;
    for (int nb = gw * 8; nb < NN; nb += nw * 8) {
        int n = nb + ns;
        int r0 = row_ptr[n], r1 = row_ptr[n + 1];
        float acc[8];
#pragma unroll
        for (int k = 0; k < 8; k++) acc[k] = 0.f;
        // self-loop row: wave reads 8 consecutive rows = 1KB coalesced
        {
            uint4 sa = *(const uint4*)(y + (size_t)n * HID + c * 8);
            rG_add8(acc, sa);
        }
        int e = r0;
        while (e + 8 <= r1) {   // 8 independent 16B gathers in flight
            int s[8];
#pragma unroll
            for (int i = 0; i < 8; i++) s[i] = col_src[e + i];
            uint4 a[8];
#pragma unroll
            for (int i = 0; i < 8; i++)
                a[i] = *(const uint4*)(y + (size_t)s[i] * HID + c * 8);
#pragma unroll
            for (int i = 0; i < 8; i++) rG_add8(acc, a[i]);
            e += 8;
        }
        if (e < r1) {           // clamped masked tail (dup loads are L1 hits)
            int lim = r1 - 1;
            int s[8];
#pragma unroll
            for (int i = 0; i < 8; i++) s[i] = col_src[min(e + i, lim)];
            uint4 a[8];
#pragma unroll
            for (int i = 0; i < 8; i++)
                a[i] = *(const uint4*)(y + (size_t)s[i] * HID + c * 8);
#pragma unroll
            for (int i = 0; i < 8; i++)
                rG_acc8(acc, a[i], (e + i < r1) ? 1.f : 0.f);
        }
        float dv = dinv[n];
        unsigned ob[4];
#pragma unroll
        for (int q = 0; q < 4; q++) {
            float o0 = acc[2 * q] * dv + bl[2 * q];
            float o1 = acc[2 * q + 1] * dv + bl[2 * q + 1];
            ssum[2 * q] += o0; ssq[2 * q] += o0 * o0;
            ssum[2 * q + 1] += o1; ssq[2 * q + 1] += o1 * o1;
            bf16 h0 = f2b(o0), h1 = f2b(o1);
            unsigned short* hp0 = (unsigned short*)&h0;
            unsigned short* hp1 = (unsigned short*)&h1;
            ob[q] = (unsigned)(*hp0) | ((unsigned)(*hp1) << 16);
        }
        *(uint4*)(outb + (size_t)n * HID + c * 8) = *(uint4*)ob;
    }
    // reduce stats across the 8 node-slot groups (lanes sharing c)
#pragma unroll
    for (int m = 8; m <= 32; m <<= 1) {
#pragma unroll
        for (int k = 0; k < 8; k++) {
            ssum[k] += __shfl_xor(ssum[k], m);
            ssq[k] += __shfl_xor(ssq[k], m);
        }
    }
    __shared__ float ls[64], lq[64];
    if (t < 64) { ls[t] = 0.f; lq[t] = 0.f; }
    __syncthreads();
    if (ns == 0) {
#pragma unroll
        for (int k = 0; k < 8; k++) {
            atomicAdd(&ls[c * 8 + k], ssum[k]);
            atomicAdd(&lq[c * 8 + k], ssq[k]);
        }
    }
    __syncthreads();
    if (t < 64) {
        atomicAdd(&stats[t], ls[t]);
        atomicAdd(&stats[64 + t], lq[t]);
    }
}

// ---------- BN1 + ReLU + (h @ W2) * dinv ----------
__global__ __launch_bounds__(256) void rG_bnmm(const bf16* outb, const float* stats,
                                               const float* gamma, const float* beta,
                                               const float* W2, const float* dinv,
                                               bf16* y) {
    __shared__ float w2s[HID * HID];
    __shared__ float hs[64 * (HID + 1)];
    __shared__ float scale[HID], shift[HID];
    int t = threadIdx.x;
    if (t < HID) {
        float mu = stats[t] * (1.0f / NN);
        float var = stats[64 + t] * (1.0f / NN) - mu * mu;
        float rs = rsqrtf(var + EPS);
        float g = gamma[t];
        scale[t] = rs * g;
        shift[t] = beta[t] - mu * rs * g;
    }
    for (int i = t; i < HID * HID; i += 256) w2s[i] = W2[i];
    __syncthreads();
    int nb = blockIdx.x * 64;
    for (int i = t; i < 64 * HID; i += 256) {
        int k = i & 63;
        float v = b2f(outb[(size_t)nb * HID + i]);
        hs[(i >> 6) * (HID + 1) + k] = fmaxf(v * scale[k] + shift[k], 0.f);
    }
    __syncthreads();
    int node = t >> 2, fg = t & 3;
    float acc[16];
    for (int j = 0; j < 16; j++) acc[j] = 0.f;
    for (int k = 0; k < HID; k++) {
        float hv = hs[node * (HID + 1) + k];
        for (int j = 0; j < 16; j++) acc[j] += hv * w2s[k * HID + fg * 16 + j];
    }
    int n = nb + node;
    float dv = dinv[n];
    for (int j = 0; j < 16; j++) y[n * HID + fg * 16 + j] = f2b(acc[j] * dv);
}

// ---------- BN2 + ReLU + mean pool + concat ----------
__global__ __launch_bounds__(256) void rG_pool(const bf16* outb, const float* stats,
                                               const float* gamma, const float* beta,
                                               const int* graph_ptr, const float* gf,
                                               float* comb) {
    __shared__ float scale[HID], shift[HID];
    __shared__ float red[256];
    int t = threadIdx.x;
    int g = blockIdx.x;
    if (t < HID) {
        float mu = stats[t] * (1.0f / NN);
        float var = stats[64 + t] * (1.0f / NN) - mu * mu;
        float rs = rsqrtf(var + EPS);
        float ga = gamma[t];
        scale[t] = rs * ga;
        shift[t] = beta[t] - mu * rs * ga;
    }
    __syncthreads();
    int g0 = graph_ptr[g], g1 = graph_ptr[g + 1];
    int f = t & 63, j = t >> 6;
    float acc = 0.f;
    for (int n = g0 + j; n < g1; n += 4)
        acc += fmaxf(b2f(outb[(size_t)n * HID + f]) * scale[f] + shift[f], 0.f);
    red[t] = acc;
    __syncthreads();
    if (t < 64) {
        float tot = red[t] + red[64 + t] + red[128 + t] + red[192 + t];
        float c = (float)(g1 - g0);
        comb[g * 80 + t] = tot / fmaxf(c, 1.0f);
    }
    if (t < GFC) comb[g * 80 + HID + t] = gf[g * GFC + t];
}

// ---------- head: f32 output ----------
__global__ void rG_head(const float* comb,
                        const float* Wo1, const float* bo1,
                        const float* Wo2, const float* bo2,
                        const float* Wb1, const float* bb1,
                        const float* Wb2, const float* bb2,
                        int* err, float* out) {
    int tid = blockIdx.x * blockDim.x + threadIdx.x;
    if (tid >= 2048) return;
    int g = tid & 1023, br = tid >> 10;
    const float* W1 = br ? Wb1 : Wo1;
    const float* B1 = br ? bb1 : bo1;
    const float* W2 = br ? Wb2 : Wo2;
    const float* B2 = br ? bb2 : bo2;
    float val = B2[0];
    for (int j = 0; j < 32; j++) {
        float z = B1[j];
        for (int k = 0; k < 80; k++) z += comb[g * 80 + k] * W1[k * 32 + j];
        val += fmaxf(z, 0.f) * W2[j];
    }
    int code = atomicAdd(err, 0);
    out[br * NG + g] = code ? (float)code : val;
}

extern "C" void kernel_launch(void* const* d_in, const int* in_sizes, int n_in,
                              void* d_out, int out_size, void* d_ws, size_t ws_size,
                              hipStream_t stream) {
    const int expect[20] = {
        NN * FIN, 2 * NE, NN, NG * GFC,
        FIN * HID, HID, HID, HID,
        HID * HID, HID, HID, HID,
        (HID + GFC) * (HID / 2), HID / 2, HID / 2, 1,
        (HID + GFC) * (HID / 2), HID / 2, HID / 2, 1
    };
    if (n_in != 20) {
        rG_code<<<8, 256, 0, stream>>>(9000.0f + (float)n_in, (float*)d_out);
        return;
    }
    for (int i = 0; i < 20; i++) {
        if (in_sizes[i] != expect[i]) {
            rG_code<<<8, 256, 0, stream>>>(8000.0f + 50.0f * (float)i, (float*)d_out);
            return;
        }
    }
    if (out_size != 2048) {
        rG_code<<<8, 256, 0, stream>>>(9900.0f, (float*)d_out);
        return;
    }

    const float* x    = (const float*)d_in[0];
    const int*   ei   = (const int*)d_in[1];
    const int*   bat  = (const int*)d_in[2];
    const float* gf   = (const float*)d_in[3];
    const float* W1   = (const float*)d_in[4];
    const float* b1   = (const float*)d_in[5];
    const float* g1   = (const float*)d_in[6];
    const float* be1  = (const float*)d_in[7];
    const float* W2   = (const float*)d_in[8];
    const float* b2   = (const float*)d_in[9];
    const float* g2   = (const float*)d_in[10];
    const float* be2  = (const float*)d_in[11];
    const float* Wo1  = (const float*)d_in[12];
    const float* bo1  = (const float*)d_in[13];
    const float* Wo2  = (const float*)d_in[14];
    const float* bo2  = (const float*)d_in[15];
    const float* Wb1  = (const float*)d_in[16];
    const float* bb1  = (const float*)d_in[17];
    const float* Wb2  = (const float*)d_in[18];
    const float* bb2  = (const float*)d_in[19];

    char* base = (char*)d_ws;
    int*   err        = (int*)base;                        // 64 ints, zeroed
    int*   graph_cnt  = err + 64;                          // NG, zeroed
    float* stats      = (float*)(graph_cnt + NG);          // 256, zeroed
    int*   bin_cnt    = (int*)(stats + 256);               // 256, zeroed
    char*  zero_end   = (char*)(bin_cnt + 256);
    int*   bucket_base = bin_cnt + 256;                    // 257 (+pad 320)
    float* dinv       = (float*)(bucket_base + 320);       // NN
    int*   row_ptr    = (int*)(dinv + NN);                 // NN+1 (+pad)
    int*   graph_ptr  = row_ptr + NN + 64;                 // NG+1 (+pad)
    int*   col_src    = graph_ptr + NG + 64;               // NE
    bf16*  ybuf       = (bf16*)(col_src + NE);             // NN*HID (bin aliases here)
    bf16*  outb       = ybuf + (size_t)NN * HID;
    float* comb       = (float*)(outb + (size_t)NN * HID);
    char*  wend       = (char*)(comb + NG * 80);
    unsigned* bin     = (unsigned*)ybuf;                   // 10.49 MB < ybuf 16.78 MB
    size_t need = (size_t)(wend - base);
    if (ws_size < need) {
        rG_code<<<8, 256, 0, stream>>>(4000.0f + 4.0f * (float)(ws_size >> 20), (float*)d_out);
        return;
    }

    hipMemsetAsync(d_ws, 0, (size_t)(zero_end - base), stream);

    rG_bhist<<<NN / 256, 256, 0, stream>>>(bat, graph_cnt, err);
    rG_bin<<<NE / 8192, 256, 0, stream>>>(ei, bin, bin_cnt, err);
    rG_bscan<<<1, 256, 0, stream>>>(bin_cnt, bucket_base, row_ptr, err);
    rG_scan_graphs<<<1, 1024, 0, stream>>>(graph_cnt, graph_ptr, err);
    rG_sort<<<256, 256, 0, stream>>>(bin, bin_cnt, bucket_base, row_ptr, dinv, col_src);

    rG_xw1<<<NN / 64, 256, 0, stream>>>(x, W1, dinv, ybuf);
    rG_agg<<<2048, 256, 0, stream>>>(row_ptr, col_src, dinv, b1, ybuf, outb, stats);
    rG_bnmm<<<NN / 64, 256, 0, stream>>>(outb, stats, g1, be1, W2, dinv, ybuf);
    rG_agg<<<2048, 256, 0, stream>>>(row_ptr, col_src, dinv, b2, ybuf, outb, stats + 128);
    rG_pool<<<NG, 256, 0, stream>>>(outb, stats + 128, g2, be2, graph_ptr, gf, comb);
    rG_head<<<8, 256, 0, stream>>>(comb, Wo1, bo1, Wo2, bo2, Wb1, bb1, Wb2, bb2,
                                   err, (float*)d_out);
}

// Round 2
// 424.328 us; speedup vs baseline: 1.2728x; 1.1393x over previous
//
#include <hip/hip_runtime.h>
#include <hip/hip_bf16.h>

#define NN 131072
#define NE 2097152
#define FIN 32
#define HID 64
#define GFC 16
#define NG 1024
#define EPS 1e-5f
#define BCAP 9216    // per-bucket bin capacity (mean 8192, +11 sigma)
#define PBCAP 12800  // padded bucket capacity: BCAP + 512*7 = 12800 exactly

typedef __hip_bfloat16 bf16;

__device__ __forceinline__ float b2f(bf16 v) { return __bfloat162float(v); }
__device__ __forceinline__ bf16 f2b(float v) { return __float2bfloat16(v); }
__device__ __forceinline__ void rG_err(int* err, int code) { atomicCAS(err, 0, code); }

// accumulate 8 bf16 (as uint4) into acc[8], no mask
__device__ __forceinline__ void rG_add8(float* acc, uint4 a) {
    const unsigned* u = (const unsigned*)&a;
#pragma unroll
    for (int q = 0; q < 4; q++) {
        acc[2 * q]     += __uint_as_float(u[q] << 16);
        acc[2 * q + 1] += __uint_as_float(u[q] & 0xFFFF0000u);
    }
}

// ---------- broadcast diagnostic code (f32 output) ----------
__global__ void rG_code(float code, float* out) {
    int i = blockIdx.x * blockDim.x + threadIdx.x;
    if (i < 2048) out[i] = code;
}

// ---------- batch histogram (batch is sorted -> run-length atomics) ----------
__global__ void rG_bhist(const int* batch, int* graph_cnt, int* err) {
    int n = blockIdx.x * blockDim.x + threadIdx.x;   // grid covers NN exactly
    int lane = threadIdx.x & 63;
    int bg = batch[n];
    if ((unsigned)bg >= NG) { rG_err(err, 3100); bg = 0; }
    int bgp = __shfl_up(bg, 1);
    bool head = (lane == 0) || (bgp != bg);
    int bgn = __shfl_down(bg, 1);
    bool last = (lane == 63) || (bgn != bg);
    unsigned long long hm = __ballot(head);
    if (last) {
        unsigned long long below = (lane == 63) ? hm : (hm & ((1ULL << (lane + 1)) - 1ULL));
        int start = 63 - __clzll(below);
        atomicAdd(&graph_cnt[bg], lane - start + 1);
    }
}

// ---------- bin edges into 256 coarse buckets (dst>>9) ----------
// LDS counting-sort per block, then coalesced run write-out (runs avg 32 x 4B).
__global__ __launch_bounds__(256) void rG_bin(const int* ei, unsigned* bin, int* bin_cnt,
                                              int* err) {
    __shared__ unsigned lsort[8192];
    __shared__ unsigned char bof[8192];
    __shared__ int h[256];
    __shared__ int h2[256];
    __shared__ int lbase[256];
    __shared__ int gbase[256];
    int t = threadIdx.x;
    h[t] = 0;
    h2[t] = 0;
    __syncthreads();
    int start = blockIdx.x * 8192;
    unsigned vals[32];
    unsigned char bks[32];
#pragma unroll
    for (int i = 0; i < 32; i++) {
        int e = start + i * 256 + t;
        int s = ei[e];
        int d = ei[NE + e];
        if ((unsigned)s >= NN || (unsigned)d >= NN) { rG_err(err, 3000); s = 0; d = 0; }
        int b = d >> 9;
        vals[i] = ((unsigned)(d & 511) << 17) | (unsigned)s;
        bks[i] = (unsigned char)b;
        atomicAdd(&h[b], 1);
    }
    __syncthreads();
    // inclusive scan of h into lbase
    lbase[t] = h[t];
    __syncthreads();
    for (int off = 1; off < 256; off <<= 1) {
        int v = (t >= off) ? lbase[t - off] : 0;
        __syncthreads();
        lbase[t] += v;
        __syncthreads();
    }
    gbase[t] = atomicAdd(&bin_cnt[t], h[t]);
    lbase[t] -= h[t];   // exclusive
    __syncthreads();
    // scatter into LDS, sorted by bucket
#pragma unroll
    for (int i = 0; i < 32; i++) {
        int b = bks[i];
        int r = atomicAdd(&h2[b], 1);
        int pos = lbase[b] + r;
        lsort[pos] = vals[i];
        bof[pos] = (unsigned char)b;
    }
    __syncthreads();
    // coalesced copy-out: consecutive i within a run -> consecutive global addrs
    for (int i = t; i < 8192; i += 256) {
        int b = bof[i];
        int p = gbase[b] + (i - lbase[b]);
        if (p >= BCAP) { rG_err(err, 3800); continue; }
        bin[b * BCAP + p] = lsort[i];
    }
}

// ---------- validate bucket totals ----------
__global__ void rG_bscan(const int* bin_cnt, int* err) {
    __shared__ int sh[256];
    int t = threadIdx.x;
    sh[t] = bin_cnt[t];
    __syncthreads();
    for (int off = 128; off > 0; off >>= 1) {
        if (t < off) sh[t] += sh[t + off];
        __syncthreads();
    }
    if (t == 0 && sh[0] != NE) rG_err(err, 2000);
}

// ---------- per-bucket: count 512 locals, 8-pad, scan -> row_ptr/deg8/dinv, scatter
__global__ __launch_bounds__(256) void rG_sort(const unsigned* bin, const int* bin_cnt,
                                               int* row_ptr, int* deg8, float* dinv,
                                               int* col_src) {
    __shared__ int cnt[512];
    __shared__ int sA[512];
    __shared__ int sB[512];
    int t = threadIdx.x;
    int b = blockIdx.x;
    for (int i = t; i < 512; i += 256) cnt[i] = 0;
    __syncthreads();
    int m = bin_cnt[b];
    if (m > BCAP) m = BCAP;
    // pass 1: count dst-locals
    for (int j = t; j < m; j += 256) {
        int dl = bin[b * BCAP + j] >> 17;
        atomicAdd(&cnt[dl], 1);
    }
    __syncthreads();
    // inclusive scan of PADDED counts (multiples of 8)
    for (int i = t; i < 512; i += 256) sA[i] = (cnt[i] + 7) & ~7;
    __syncthreads();
    int* src = sA;
    int* dst = sB;
    for (int off = 1; off < 512; off <<= 1) {
        for (int i = t; i < 512; i += 256)
            dst[i] = src[i] + ((i >= off) ? src[i - off] : 0);
        __syncthreads();
        int* tmp = src; src = dst; dst = tmp;
    }
    // src = inclusive scan of cnt8
    int gb = b * PBCAP;
    for (int i = t; i < 512; i += 256) {
        int c = cnt[i];
        int c8 = (c + 7) & ~7;
        int bas = gb + src[i] - c8;
        dst[i] = bas;                       // dst buffer now holds bases
        row_ptr[b * 512 + i] = bas;
        deg8[b * 512 + i] = c8;
        dinv[b * 512 + i] = rsqrtf((float)c + 1.0f);
        for (int k = c; k < c8; k++) col_src[bas + k] = NN;  // sentinel -> zero row
    }
    __syncthreads();
    for (int i = t; i < 512; i += 256) cnt[i] = 0;  // reuse as cursor
    __syncthreads();
    // pass 2: scatter
    for (int j = t; j < m; j += 256) {
        unsigned v = bin[b * BCAP + j];
        int dl = v >> 17;
        int s = (int)(v & 0x1FFFFu);
        int r = atomicAdd(&cnt[dl], 1);
        col_src[dst[dl] + r] = s;
    }
}

// ---------- scan graph counts ----------
__global__ void rG_scan_graphs(const int* cnt, int* ptr, int* err) {
    __shared__ int part[1024];
    int t = threadIdx.x;
    int s = cnt[t];
    part[t] = s;
    __syncthreads();
    for (int off = 1; off < 1024; off <<= 1) {
        int v = (t >= off) ? part[t - off] : 0;
        __syncthreads();
        part[t] += v;
        __syncthreads();
    }
    ptr[t] = part[t] - s;
    if (t == 1023) {
        ptr[1024] = part[1023];
        if (part[1023] != NN) rG_err(err, 2500);
    }
}

// ---------- y = (x @ W1) * dinv (bf16 staging); also zeroes sentinel row NN ---
__global__ __launch_bounds__(256) void rG_xw1(const float* x, const float* W1,
                                              const float* dinv, bf16* y) {
    __shared__ float ws[FIN * HID];
    __shared__ float xs[64 * (FIN + 1)];
    int t = threadIdx.x;
    if (blockIdx.x == 0 && t < HID) y[(size_t)NN * HID + t] = f2b(0.f);
    for (int i = t; i < FIN * HID; i += 256) ws[i] = W1[i];
    int nb = blockIdx.x * 64;
    for (int i = t; i < 64 * FIN; i += 256) {
        int n = i / FIN, k = i % FIN;
        xs[n * (FIN + 1) + k] = x[nb * FIN + i];
    }
    __syncthreads();
    int node = t >> 2, fg = t & 3;
    float acc[16];
    for (int j = 0; j < 16; j++) acc[j] = 0.f;
    for (int k = 0; k < FIN; k++) {
        float xv = xs[node * (FIN + 1) + k];
        for (int j = 0; j < 16; j++) acc[j] += xv * ws[k * HID + fg * 16 + j];
    }
    int n = nb + node;
    float dv = dinv[n];
    for (int j = 0; j < 16; j++) y[n * HID + fg * 16 + j] = f2b(acc[j] * dv);
}

// ---------- CSR aggregation: 8 nodes/wave, 8-aligned padded rows -------------
// lane = ns*8 + c. Rows padded to multiples of 8 with sentinel NN (zero y-row):
// no masked tail, no divergent tail path. col_src batch = 2 aligned uint4 loads,
// prefetched one batch ahead so only gather latency sits on the critical path.
__global__ __launch_bounds__(256) void rG_agg(const int* row_ptr, const int* deg8,
                                              const int* col_src,
                                              const float* dinv, const float* bias,
                                              const bf16* y, bf16* outb, float* stats) {
    int t = threadIdx.x;
    int lane = t & 63, wave = t >> 6;
    int ns = lane >> 3;
    int c = lane & 7;
    float bl[8];
#pragma unroll
    for (int k = 0; k < 8; k++) bl[k] = bias[c * 8 + k];
    float ssum[8], ssq[8];
#pragma unroll
    for (int k = 0; k < 8; k++) { ssum[k] = 0.f; ssq[k] = 0.f; }
    int gw = blockIdx.x * 4 + wave;
    int nw = gridDim.x * 4;
    for (int nb = gw * 8; nb < NN; nb += nw * 8) {
        int n = nb + ns;
        int r0 = row_ptr[n];
        int r1 = r0 + deg8[n];
        float acc[8];
#pragma unroll
        for (int k = 0; k < 8; k++) acc[k] = 0.f;
        // self-loop row: wave reads 8 consecutive rows = 1KB coalesced;
        // overlaps the first col_src load's latency
        uint4 sa = *(const uint4*)(y + (size_t)n * HID + c * 8);
        rG_add8(acc, sa);
        uint4 cs0 = {0, 0, 0, 0}, cs1 = {0, 0, 0, 0};
        if (r0 < r1) {
            cs0 = *(const uint4*)(col_src + r0);
            cs1 = *(const uint4*)(col_src + r0 + 4);
        }
        for (int e = r0; e < r1; e += 8) {
            uint4 n0 = cs0, n1 = cs1;
            if (e + 8 < r1) {                 // prefetch next batch's indices
                n0 = *(const uint4*)(col_src + e + 8);
                n1 = *(const uint4*)(col_src + e + 12);
            }
            int idx[8] = {(int)cs0.x, (int)cs0.y, (int)cs0.z, (int)cs0.w,
                          (int)cs1.x, (int)cs1.y, (int)cs1.z, (int)cs1.w};
            uint4 a[8];
#pragma unroll
            for (int i = 0; i < 8; i++)
                a[i] = *(const uint4*)(y + (size_t)idx[i] * HID + c * 8);
#pragma unroll
            for (int i = 0; i < 8; i++) rG_add8(acc, a[i]);
            cs0 = n0; cs1 = n1;
        }
        float dv = dinv[n];
        unsigned ob[4];
#pragma unroll
        for (int q = 0; q < 4; q++) {
            float o0 = acc[2 * q] * dv + bl[2 * q];
            float o1 = acc[2 * q + 1] * dv + bl[2 * q + 1];
            ssum[2 * q] += o0; ssq[2 * q] += o0 * o0;
            ssum[2 * q + 1] += o1; ssq[2 * q + 1] += o1 * o1;
            bf16 h0 = f2b(o0), h1 = f2b(o1);
            unsigned short* hp0 = (unsigned short*)&h0;
            unsigned short* hp1 = (unsigned short*)&h1;
            ob[q] = (unsigned)(*hp0) | ((unsigned)(*hp1) << 16);
        }
        *(uint4*)(outb + (size_t)n * HID + c * 8) = *(uint4*)ob;
    }
    // reduce stats across the 8 node-slot groups (lanes sharing c)
#pragma unroll
    for (int m = 8; m <= 32; m <<= 1) {
#pragma unroll
        for (int k = 0; k < 8; k++) {
            ssum[k] += __shfl_xor(ssum[k], m);
            ssq[k] += __shfl_xor(ssq[k], m);
        }
    }
    __shared__ float ls[64], lq[64];
    if (t < 64) { ls[t] = 0.f; lq[t] = 0.f; }
    __syncthreads();
    if (ns == 0) {
#pragma unroll
        for (int k = 0; k < 8; k++) {
            atomicAdd(&ls[c * 8 + k], ssum[k]);
            atomicAdd(&lq[c * 8 + k], ssq[k]);
        }
    }
    __syncthreads();
    if (t < 64) {
        atomicAdd(&stats[t], ls[t]);
        atomicAdd(&stats[64 + t], lq[t]);
    }
}

// ---------- BN1 + ReLU + (h @ W2) * dinv ----------
__global__ __launch_bounds__(256) void rG_bnmm(const bf16* outb, const float* stats,
                                               const float* gamma, const float* beta,
                                               const float* W2, const float* dinv,
                                               bf16* y) {
    __shared__ float w2s[HID * HID];
    __shared__ float hs[64 * (HID + 1)];
    __shared__ float scale[HID], shift[HID];
    int t = threadIdx.x;
    if (t < HID) {
        float mu = stats[t] * (1.0f / NN);
        float var = stats[64 + t] * (1.0f / NN) - mu * mu;
        float rs = rsqrtf(var + EPS);
        float g = gamma[t];
        scale[t] = rs * g;
        shift[t] = beta[t] - mu * rs * g;
    }
    for (int i = t; i < HID * HID; i += 256) w2s[i] = W2[i];
    __syncthreads();
    int nb = blockIdx.x * 64;
    for (int i = t; i < 64 * HID; i += 256) {
        int k = i & 63;
        float v = b2f(outb[(size_t)nb * HID + i]);
        hs[(i >> 6) * (HID + 1) + k] = fmaxf(v * scale[k] + shift[k], 0.f);
    }
    __syncthreads();
    int node = t >> 2, fg = t & 3;
    float acc[16];
    for (int j = 0; j < 16; j++) acc[j] = 0.f;
    for (int k = 0; k < HID; k++) {
        float hv = hs[node * (HID + 1) + k];
        for (int j = 0; j < 16; j++) acc[j] += hv * w2s[k * HID + fg * 16 + j];
    }
    int n = nb + node;
    float dv = dinv[n];
    for (int j = 0; j < 16; j++) y[n * HID + fg * 16 + j] = f2b(acc[j] * dv);
}

// ---------- BN2 + ReLU + mean pool + concat ----------
__global__ __launch_bounds__(256) void rG_pool(const bf16* outb, const float* stats,
                                               const float* gamma, const float* beta,
                                               const int* graph_ptr, const float* gf,
                                               float* comb) {
    __shared__ float scale[HID], shift[HID];
    __shared__ float red[256];
    int t = threadIdx.x;
    int g = blockIdx.x;
    if (t < HID) {
        float mu = stats[t] * (1.0f / NN);
        float var = stats[64 + t] * (1.0f / NN) - mu * mu;
        float rs = rsqrtf(var + EPS);
        float ga = gamma[t];
        scale[t] = rs * ga;
        shift[t] = beta[t] - mu * rs * ga;
    }
    __syncthreads();
    int g0 = graph_ptr[g], g1 = graph_ptr[g + 1];
    int f = t & 63, j = t >> 6;
    float acc = 0.f;
    for (int n = g0 + j; n < g1; n += 4)
        acc += fmaxf(b2f(outb[(size_t)n * HID + f]) * scale[f] + shift[f], 0.f);
    red[t] = acc;
    __syncthreads();
    if (t < 64) {
        float tot = red[t] + red[64 + t] + red[128 + t] + red[192 + t];
        float c = (float)(g1 - g0);
        comb[g * 80 + t] = tot / fmaxf(c, 1.0f);
    }
    if (t < GFC) comb[g * 80 + HID + t] = gf[g * GFC + t];
}

// ---------- head: f32 output ----------
__global__ void rG_head(const float* comb,
                        const float* Wo1, const float* bo1,
                        const float* Wo2, const float* bo2,
                        const float* Wb1, const float* bb1,
                        const float* Wb2, const float* bb2,
                        int* err, float* out) {
    int tid = blockIdx.x * blockDim.x + threadIdx.x;
    if (tid >= 2048) return;
    int g = tid & 1023, br = tid >> 10;
    const float* W1 = br ? Wb1 : Wo1;
    const float* B1 = br ? bb1 : bo1;
    const float* W2 = br ? Wb2 : Wo2;
    const float* B2 = br ? bb2 : bo2;
    float val = B2[0];
    for (int j = 0; j < 32; j++) {
        float z = B1[j];
        for (int k = 0; k < 80; k++) z += comb[g * 80 + k] * W1[k * 32 + j];
        val += fmaxf(z, 0.f) * W2[j];
    }
    int code = atomicAdd(err, 0);
    out[br * NG + g] = code ? (float)code : val;
}

extern "C" void kernel_launch(void* const* d_in, const int* in_sizes, int n_in,
                              void* d_out, int out_size, void* d_ws, size_t ws_size,
                              hipStream_t stream) {
    const int expect[20] = {
        NN * FIN, 2 * NE, NN, NG * GFC,
        FIN * HID, HID, HID, HID,
        HID * HID, HID, HID, HID,
        (HID + GFC) * (HID / 2), HID / 2, HID / 2, 1,
        (HID + GFC) * (HID / 2), HID / 2, HID / 2, 1
    };
    if (n_in != 20) {
        rG_code<<<8, 256, 0, stream>>>(9000.0f + (float)n_in, (float*)d_out);
        return;
    }
    for (int i = 0; i < 20; i++) {
        if (in_sizes[i] != expect[i]) {
            rG_code<<<8, 256, 0, stream>>>(8000.0f + 50.0f * (float)i, (float*)d_out);
            return;
        }
    }
    if (out_size != 2048) {
        rG_code<<<8, 256, 0, stream>>>(9900.0f, (float*)d_out);
        return;
    }

    const float* x    = (const float*)d_in[0];
    const int*   ei   = (const int*)d_in[1];
    const int*   bat  = (const int*)d_in[2];
    const float* gf   = (const float*)d_in[3];
    const float* W1   = (const float*)d_in[4];
    const float* b1   = (const float*)d_in[5];
    const float* g1   = (const float*)d_in[6];
    const float* be1  = (const float*)d_in[7];
    const float* W2   = (const float*)d_in[8];
    const float* b2   = (const float*)d_in[9];
    const float* g2   = (const float*)d_in[10];
    const float* be2  = (const float*)d_in[11];
    const float* Wo1  = (const float*)d_in[12];
    const float* bo1  = (const float*)d_in[13];
    const float* Wo2  = (const float*)d_in[14];
    const float* bo2  = (const float*)d_in[15];
    const float* Wb1  = (const float*)d_in[16];
    const float* bb1  = (const float*)d_in[17];
    const float* Wb2  = (const float*)d_in[18];
    const float* bb2  = (const float*)d_in[19];

    char* base = (char*)d_ws;
    int*   err        = (int*)base;                        // 64 ints, zeroed
    int*   graph_cnt  = err + 64;                          // NG, zeroed
    float* stats      = (float*)(graph_cnt + NG);          // 256, zeroed
    int*   bin_cnt    = (int*)(stats + 256);               // 256, zeroed
    char*  zero_end   = (char*)(bin_cnt + 256);
    float* dinv       = (float*)(bin_cnt + 256);           // NN
    int*   row_ptr    = (int*)(dinv + NN);                 // NN+64
    int*   deg8       = row_ptr + NN + 64;                 // NN (padded degree)
    int*   graph_ptr  = deg8 + NN;                         // NG+64
    int*   col_src    = graph_ptr + NG + 64;               // 256*PBCAP (8-aligned rows)
    bf16*  ybuf       = (bf16*)(col_src + 256 * PBCAP);    // (NN+1)*HID, row NN = zeros
    bf16*  outb       = ybuf + (size_t)(NN + 1) * HID;
    float* comb       = (float*)(outb + (size_t)NN * HID);
    char*  wend       = (char*)(comb + NG * 80);
    unsigned* bin     = (unsigned*)ybuf;                   // 9.44 MB < ybuf 16.78 MB
    size_t need = (size_t)(wend - base);
    if (ws_size < need) {
        rG_code<<<8, 256, 0, stream>>>(4000.0f + 4.0f * (float)(ws_size >> 20), (float*)d_out);
        return;
    }

    hipMemsetAsync(d_ws, 0, (size_t)(zero_end - base), stream);

    rG_bhist<<<NN / 256, 256, 0, stream>>>(bat, graph_cnt, err);
    rG_bin<<<NE / 8192, 256, 0, stream>>>(ei, bin, bin_cnt, err);
    rG_bscan<<<1, 256, 0, stream>>>(bin_cnt, err);
    rG_scan_graphs<<<1, 1024, 0, stream>>>(graph_cnt, graph_ptr, err);
    rG_sort<<<256, 256, 0, stream>>>(bin, bin_cnt, row_ptr, deg8, dinv, col_src);

    rG_xw1<<<NN / 64, 256, 0, stream>>>(x, W1, dinv, ybuf);
    rG_agg<<<2048, 256, 0, stream>>>(row_ptr, deg8, col_src, dinv, b1, ybuf, outb, stats);
    rG_bnmm<<<NN / 64, 256, 0, stream>>>(outb, stats, g1, be1, W2, dinv, ybuf);
    rG_agg<<<2048, 256, 0, stream>>>(row_ptr, deg8, col_src, dinv, b2, ybuf, outb, stats + 128);
    rG_pool<<<NG, 256, 0, stream>>>(outb, stats + 128, g2, be2, graph_ptr, gf, comb);
    rG_head<<<8, 256, 0, stream>>>(comb, Wo1, bo1, Wo2, bo2, Wb1, bb1, Wb2, bb2,
                                   err, (float*)d_out);
}

// Round 3
// 359.690 us; speedup vs baseline: 1.5015x; 1.1797x over previous
//
#include <hip/hip_runtime.h>
#include <hip/hip_bf16.h>

#define NN 131072
#define NE 2097152
#define FIN 32
#define HID 64
#define GFC 16
#define NG 1024
#define EPS 1e-5f
#define BCAP 9216    // per-bucket bin capacity (mean 8192, +11 sigma)
#define PBCAP 12800  // padded bucket capacity: BCAP + 512*7 = 12800 exactly

typedef __hip_bfloat16 bf16;

__device__ __forceinline__ float b2f(bf16 v) { return __bfloat162float(v); }
__device__ __forceinline__ bf16 f2b(float v) { return __float2bfloat16(v); }
__device__ __forceinline__ void rG_err(int* err, int code) { atomicCAS(err, 0, code); }

// accumulate 8 bf16 (as uint4) into acc[8], no mask
__device__ __forceinline__ void rG_add8(float* acc, uint4 a) {
    const unsigned* u = (const unsigned*)&a;
#pragma unroll
    for (int q = 0; q < 4; q++) {
        acc[2 * q]     += __uint_as_float(u[q] << 16);
        acc[2 * q + 1] += __uint_as_float(u[q] & 0xFFFF0000u);
    }
}

// ---------- broadcast diagnostic code (f32 output) ----------
__global__ void rG_code(float code, float* out) {
    int i = blockIdx.x * blockDim.x + threadIdx.x;
    if (i < 2048) out[i] = code;
}

// ---------- batch histogram (batch is sorted -> run-length atomics) ----------
__global__ void rG_bhist(const int* batch, int* graph_cnt, int* err) {
    int n = blockIdx.x * blockDim.x + threadIdx.x;   // grid covers NN exactly
    int lane = threadIdx.x & 63;
    int bg = batch[n];
    if ((unsigned)bg >= NG) { rG_err(err, 3100); bg = 0; }
    int bgp = __shfl_up(bg, 1);
    bool head = (lane == 0) || (bgp != bg);
    int bgn = __shfl_down(bg, 1);
    bool last = (lane == 63) || (bgn != bg);
    unsigned long long hm = __ballot(head);
    if (last) {
        unsigned long long below = (lane == 63) ? hm : (hm & ((1ULL << (lane + 1)) - 1ULL));
        int start = 63 - __clzll(below);
        atomicAdd(&graph_cnt[bg], lane - start + 1);
    }
}

// ---------- bin edges into 256 coarse buckets (dst>>9) ----------
// LDS counting-sort per block, then coalesced run write-out (runs avg 32 x 4B).
__global__ __launch_bounds__(256) void rG_bin(const int* ei, unsigned* bin, int* bin_cnt,
                                              int* err) {
    __shared__ unsigned lsort[8192];
    __shared__ unsigned char bof[8192];
    __shared__ int h[256];
    __shared__ int h2[256];
    __shared__ int lbase[256];
    __shared__ int gbase[256];
    int t = threadIdx.x;
    h[t] = 0;
    h2[t] = 0;
    __syncthreads();
    int start = blockIdx.x * 8192;
    unsigned vals[32];
    unsigned char bks[32];
#pragma unroll
    for (int i = 0; i < 32; i++) {
        int e = start + i * 256 + t;
        int s = ei[e];
        int d = ei[NE + e];
        if ((unsigned)s >= NN || (unsigned)d >= NN) { rG_err(err, 3000); s = 0; d = 0; }
        int b = d >> 9;
        vals[i] = ((unsigned)(d & 511) << 17) | (unsigned)s;
        bks[i] = (unsigned char)b;
        atomicAdd(&h[b], 1);
    }
    __syncthreads();
    // inclusive scan of h into lbase
    lbase[t] = h[t];
    __syncthreads();
    for (int off = 1; off < 256; off <<= 1) {
        int v = (t >= off) ? lbase[t - off] : 0;
        __syncthreads();
        lbase[t] += v;
        __syncthreads();
    }
    gbase[t] = atomicAdd(&bin_cnt[t], h[t]);
    lbase[t] -= h[t];   // exclusive
    __syncthreads();
    // scatter into LDS, sorted by bucket
#pragma unroll
    for (int i = 0; i < 32; i++) {
        int b = bks[i];
        int r = atomicAdd(&h2[b], 1);
        int pos = lbase[b] + r;
        lsort[pos] = vals[i];
        bof[pos] = (unsigned char)b;
    }
    __syncthreads();
    // coalesced copy-out: consecutive i within a run -> consecutive global addrs
    for (int i = t; i < 8192; i += 256) {
        int b = bof[i];
        int p = gbase[b] + (i - lbase[b]);
        if (p >= BCAP) { rG_err(err, 3800); continue; }
        bin[b * BCAP + p] = lsort[i];
    }
}

// ---------- validate bucket totals ----------
__global__ void rG_bscan(const int* bin_cnt, int* err) {
    __shared__ int sh[256];
    int t = threadIdx.x;
    sh[t] = bin_cnt[t];
    __syncthreads();
    for (int off = 128; off > 0; off >>= 1) {
        if (t < off) sh[t] += sh[t + off];
        __syncthreads();
    }
    if (t == 0 && sh[0] != NE) rG_err(err, 2000);
}

// ---------- per-bucket: count 512 locals, 8-pad, scan -> row_ptr/deg8/dinv, scatter
__global__ __launch_bounds__(256) void rG_sort(const unsigned* bin, const int* bin_cnt,
                                               int* row_ptr, int* deg8, float* dinv,
                                               int* col_src) {
    __shared__ int cnt[512];
    __shared__ int sA[512];
    __shared__ int sB[512];
    int t = threadIdx.x;
    int b = blockIdx.x;
    for (int i = t; i < 512; i += 256) cnt[i] = 0;
    __syncthreads();
    int m = bin_cnt[b];
    if (m > BCAP) m = BCAP;
    // pass 1: count dst-locals
    for (int j = t; j < m; j += 256) {
        int dl = bin[b * BCAP + j] >> 17;
        atomicAdd(&cnt[dl], 1);
    }
    __syncthreads();
    // inclusive scan of PADDED counts (multiples of 8)
    for (int i = t; i < 512; i += 256) sA[i] = (cnt[i] + 7) & ~7;
    __syncthreads();
    int* src = sA;
    int* dst = sB;
    for (int off = 1; off < 512; off <<= 1) {
        for (int i = t; i < 512; i += 256)
            dst[i] = src[i] + ((i >= off) ? src[i - off] : 0);
        __syncthreads();
        int* tmp = src; src = dst; dst = tmp;
    }
    // src = inclusive scan of cnt8
    int gb = b * PBCAP;
    for (int i = t; i < 512; i += 256) {
        int c = cnt[i];
        int c8 = (c + 7) & ~7;
        int bas = gb + src[i] - c8;
        dst[i] = bas;                       // dst buffer now holds bases
        row_ptr[b * 512 + i] = bas;
        deg8[b * 512 + i] = c8;
        dinv[b * 512 + i] = rsqrtf((float)c + 1.0f);
        for (int k = c; k < c8; k++) col_src[bas + k] = NN;  // sentinel -> zero row
    }
    __syncthreads();
    for (int i = t; i < 512; i += 256) cnt[i] = 0;  // reuse as cursor
    __syncthreads();
    // pass 2: scatter
    for (int j = t; j < m; j += 256) {
        unsigned v = bin[b * BCAP + j];
        int dl = v >> 17;
        int s = (int)(v & 0x1FFFFu);
        int r = atomicAdd(&cnt[dl], 1);
        col_src[dst[dl] + r] = s;
    }
}

// ---------- scan graph counts ----------
__global__ void rG_scan_graphs(const int* cnt, int* ptr, int* err) {
    __shared__ int part[1024];
    int t = threadIdx.x;
    int s = cnt[t];
    part[t] = s;
    __syncthreads();
    for (int off = 1; off < 1024; off <<= 1) {
        int v = (t >= off) ? part[t - off] : 0;
        __syncthreads();
        part[t] += v;
        __syncthreads();
    }
    ptr[t] = part[t] - s;
    if (t == 1023) {
        ptr[1024] = part[1023];
        if (part[1023] != NN) rG_err(err, 2500);
    }
}

// ---------- y = (x @ W1) * dinv (bf16 staging); also zeroes sentinel row NN ---
__global__ __launch_bounds__(256) void rG_xw1(const float* x, const float* W1,
                                              const float* dinv, bf16* y) {
    __shared__ float ws[FIN * HID];
    __shared__ float xs[64 * (FIN + 1)];
    int t = threadIdx.x;
    if (blockIdx.x == 0 && t < HID) y[(size_t)NN * HID + t] = f2b(0.f);
    for (int i = t; i < FIN * HID; i += 256) ws[i] = W1[i];
    int nb = blockIdx.x * 64;
    for (int i = t; i < 64 * FIN; i += 256) {
        int n = i / FIN, k = i % FIN;
        xs[n * (FIN + 1) + k] = x[nb * FIN + i];
    }
    __syncthreads();
    int node = t >> 2, fg = t & 3;
    float acc[16];
    for (int j = 0; j < 16; j++) acc[j] = 0.f;
    for (int k = 0; k < FIN; k++) {
        float xv = xs[node * (FIN + 1) + k];
        for (int j = 0; j < 16; j++) acc[j] += xv * ws[k * HID + fg * 16 + j];
    }
    int n = nb + node;
    float dv = dinv[n];
    for (int j = 0; j < 16; j++) y[n * HID + fg * 16 + j] = f2b(acc[j] * dv);
}

// ---------- CSR aggregation: 8 nodes/wave, 8-aligned padded rows -------------
// lane = ns*8 + c. Rows padded to multiples of 8 with sentinel NN (zero y-row):
// no masked tail, no divergent tail path. col_src batch = 2 aligned uint4 loads,
// prefetched one batch ahead so only gather latency sits on the critical path.
__global__ __launch_bounds__(256) void rG_agg(const int* row_ptr, const int* deg8,
                                              const int* col_src,
                                              const float* dinv, const float* bias,
                                              const bf16* y, bf16* outb, float* stats) {
    int t = threadIdx.x;
    int lane = t & 63, wave = t >> 6;
    int ns = lane >> 3;
    int c = lane & 7;
    float bl[8];
#pragma unroll
    for (int k = 0; k < 8; k++) bl[k] = bias[c * 8 + k];
    float ssum[8], ssq[8];
#pragma unroll
    for (int k = 0; k < 8; k++) { ssum[k] = 0.f; ssq[k] = 0.f; }
    int gw = blockIdx.x * 4 + wave;
    int nw = gridDim.x * 4;
    for (int nb = gw * 8; nb < NN; nb += nw * 8) {
        int n = nb + ns;
        int r0 = row_ptr[n];
        int r1 = r0 + deg8[n];
        float acc[8];
#pragma unroll
        for (int k = 0; k < 8; k++) acc[k] = 0.f;
        // self-loop row: wave reads 8 consecutive rows = 1KB coalesced;
        // overlaps the first col_src load's latency
        uint4 sa = *(const uint4*)(y + (size_t)n * HID + c * 8);
        rG_add8(acc, sa);
        uint4 cs0 = {0, 0, 0, 0}, cs1 = {0, 0, 0, 0};
        if (r0 < r1) {
            cs0 = *(const uint4*)(col_src + r0);
            cs1 = *(const uint4*)(col_src + r0 + 4);
        }
        for (int e = r0; e < r1; e += 8) {
            uint4 n0 = cs0, n1 = cs1;
            if (e + 8 < r1) {                 // prefetch next batch's indices
                n0 = *(const uint4*)(col_src + e + 8);
                n1 = *(const uint4*)(col_src + e + 12);
            }
            int idx[8] = {(int)cs0.x, (int)cs0.y, (int)cs0.z, (int)cs0.w,
                          (int)cs1.x, (int)cs1.y, (int)cs1.z, (int)cs1.w};
            uint4 a[8];
#pragma unroll
            for (int i = 0; i < 8; i++)
                a[i] = *(const uint4*)(y + (size_t)idx[i] * HID + c * 8);
#pragma unroll
            for (int i = 0; i < 8; i++) rG_add8(acc, a[i]);
            cs0 = n0; cs1 = n1;
        }
        float dv = dinv[n];
        unsigned ob[4];
#pragma unroll
        for (int q = 0; q < 4; q++) {
            float o0 = acc[2 * q] * dv + bl[2 * q];
            float o1 = acc[2 * q + 1] * dv + bl[2 * q + 1];
            ssum[2 * q] += o0; ssq[2 * q] += o0 * o0;
            ssum[2 * q + 1] += o1; ssq[2 * q + 1] += o1 * o1;
            bf16 h0 = f2b(o0), h1 = f2b(o1);
            unsigned short* hp0 = (unsigned short*)&h0;
            unsigned short* hp1 = (unsigned short*)&h1;
            ob[q] = (unsigned)(*hp0) | ((unsigned)(*hp1) << 16);
        }
        *(uint4*)(outb + (size_t)n * HID + c * 8) = *(uint4*)ob;
    }
    // reduce stats across the 8 node-slot groups (lanes sharing c)
#pragma unroll
    for (int m = 8; m <= 32; m <<= 1) {
#pragma unroll
        for (int k = 0; k < 8; k++) {
            ssum[k] += __shfl_xor(ssum[k], m);
            ssq[k] += __shfl_xor(ssq[k], m);
        }
    }
    __shared__ float ls[64], lq[64];
    if (t < 64) { ls[t] = 0.f; lq[t] = 0.f; }
    __syncthreads();
    if (ns == 0) {
#pragma unroll
        for (int k = 0; k < 8; k++) {
            atomicAdd(&ls[c * 8 + k], ssum[k]);
            atomicAdd(&lq[c * 8 + k], ssq[k]);
        }
    }
    __syncthreads();
    if (t < 64) {
        atomicAdd(&stats[t], ls[t]);
        atomicAdd(&stats[64 + t], lq[t]);
    }
}

// ---------- BN1 + ReLU + (h @ W2) * dinv ----------
__global__ __launch_bounds__(256) void rG_bnmm(const bf16* outb, const float* stats,
                                               const float* gamma, const float* beta,
                                               const float* W2, const float* dinv,
                                               bf16* y) {
    __shared__ float w2s[HID * HID];
    __shared__ float hs[64 * (HID + 1)];
    __shared__ float scale[HID], shift[HID];
    int t = threadIdx.x;
    if (t < HID) {
        float mu = stats[t] * (1.0f / NN);
        float var = stats[64 + t] * (1.0f / NN) - mu * mu;
        float rs = rsqrtf(var + EPS);
        float g = gamma[t];
        scale[t] = rs * g;
        shift[t] = beta[t] - mu * rs * g;
    }
    for (int i = t; i < HID * HID; i += 256) w2s[i] = W2[i];
    __syncthreads();
    int nb = blockIdx.x * 64;
    for (int i = t; i < 64 * HID; i += 256) {
        int k = i & 63;
        float v = b2f(outb[(size_t)nb * HID + i]);
        hs[(i >> 6) * (HID + 1) + k] = fmaxf(v * scale[k] + shift[k], 0.f);
    }
    __syncthreads();
    int node = t >> 2, fg = t & 3;
    float acc[16];
    for (int j = 0; j < 16; j++) acc[j] = 0.f;
    for (int k = 0; k < HID; k++) {
        float hv = hs[node * (HID + 1) + k];
        for (int j = 0; j < 16; j++) acc[j] += hv * w2s[k * HID + fg * 16 + j];
    }
    int n = nb + node;
    float dv = dinv[n];
    for (int j = 0; j < 16; j++) y[n * HID + fg * 16 + j] = f2b(acc[j] * dv);
}

// ---------- BN2 + ReLU + mean pool + concat + fused MLP heads ----------------
// Block g: pool its nodes into cl[0..63], stage gf into cl[64..79], then
// threads t<64 (wave 0) compute both heads: j = t&31 hidden unit, br = t>>5
// branch; 80-FMA dot from LDS + shfl reduce within each 32-lane half.
__global__ __launch_bounds__(256) void rG_pool(const bf16* outb, const float* stats,
                                               const float* gamma, const float* beta,
                                               const int* graph_ptr, const float* gf,
                                               const float* Wo1, const float* bo1,
                                               const float* Wo2, const float* bo2,
                                               const float* Wb1, const float* bb1,
                                               const float* Wb2, const float* bb2,
                                               int* err, float* out) {
    __shared__ float scale[HID], shift[HID];
    __shared__ float red[256];
    __shared__ float cl[80];
    int t = threadIdx.x;
    int g = blockIdx.x;
    if (t < HID) {
        float mu = stats[t] * (1.0f / NN);
        float var = stats[64 + t] * (1.0f / NN) - mu * mu;
        float rs = rsqrtf(var + EPS);
        float ga = gamma[t];
        scale[t] = rs * ga;
        shift[t] = beta[t] - mu * rs * ga;
    }
    __syncthreads();
    int g0 = graph_ptr[g], g1 = graph_ptr[g + 1];
    int f = t & 63, j4 = t >> 6;
    float acc = 0.f;
    for (int n = g0 + j4; n < g1; n += 4)
        acc += fmaxf(b2f(outb[(size_t)n * HID + f]) * scale[f] + shift[f], 0.f);
    red[t] = acc;
    if (t >= 64 && t < 80) cl[t] = gf[g * GFC + (t - 64)];
    __syncthreads();
    if (t < 64) {
        float tot = red[t] + red[64 + t] + red[128 + t] + red[192 + t];
        float c = (float)(g1 - g0);
        cl[t] = tot / fmaxf(c, 1.0f);
    }
    __syncthreads();
    if (t < 64) {
        int j = t & 31, br = t >> 5;
        const float* W1 = br ? Wb1 : Wo1;
        const float* B1 = br ? bb1 : bo1;
        const float* W2 = br ? Wb2 : Wo2;
        const float* B2 = br ? bb2 : bo2;
        float z = B1[j];
#pragma unroll
        for (int k = 0; k < 80; k++) z += cl[k] * W1[k * 32 + j];
        float v = fmaxf(z, 0.f) * W2[j];
        // reduce within each 32-lane half (xor masks < 32 stay in-half)
#pragma unroll
        for (int m = 1; m < 32; m <<= 1) v += __shfl_xor(v, m);
        if (j == 0) {
            int code = atomicAdd(err, 0);
            out[br * NG + g] = code ? (float)code : (v + B2[0]);
        }
    }
}

extern "C" void kernel_launch(void* const* d_in, const int* in_sizes, int n_in,
                              void* d_out, int out_size, void* d_ws, size_t ws_size,
                              hipStream_t stream) {
    const int expect[20] = {
        NN * FIN, 2 * NE, NN, NG * GFC,
        FIN * HID, HID, HID, HID,
        HID * HID, HID, HID, HID,
        (HID + GFC) * (HID / 2), HID / 2, HID / 2, 1,
        (HID + GFC) * (HID / 2), HID / 2, HID / 2, 1
    };
    if (n_in != 20) {
        rG_code<<<8, 256, 0, stream>>>(9000.0f + (float)n_in, (float*)d_out);
        return;
    }
    for (int i = 0; i < 20; i++) {
        if (in_sizes[i] != expect[i]) {
            rG_code<<<8, 256, 0, stream>>>(8000.0f + 50.0f * (float)i, (float*)d_out);
            return;
        }
    }
    if (out_size != 2048) {
        rG_code<<<8, 256, 0, stream>>>(9900.0f, (float*)d_out);
        return;
    }

    const float* x    = (const float*)d_in[0];
    const int*   ei   = (const int*)d_in[1];
    const int*   bat  = (const int*)d_in[2];
    const float* gf   = (const float*)d_in[3];
    const float* W1   = (const float*)d_in[4];
    const float* b1   = (const float*)d_in[5];
    const float* g1   = (const float*)d_in[6];
    const float* be1  = (const float*)d_in[7];
    const float* W2   = (const float*)d_in[8];
    const float* b2   = (const float*)d_in[9];
    const float* g2   = (const float*)d_in[10];
    const float* be2  = (const float*)d_in[11];
    const float* Wo1  = (const float*)d_in[12];
    const float* bo1  = (const float*)d_in[13];
    const float* Wo2  = (const float*)d_in[14];
    const float* bo2  = (const float*)d_in[15];
    const float* Wb1  = (const float*)d_in[16];
    const float* bb1  = (const float*)d_in[17];
    const float* Wb2  = (const float*)d_in[18];
    const float* bb2  = (const float*)d_in[19];

    char* base = (char*)d_ws;
    int*   err        = (int*)base;                        // 64 ints, zeroed
    int*   graph_cnt  = err + 64;                          // NG, zeroed
    float* stats      = (float*)(graph_cnt + NG);          // 256, zeroed
    int*   bin_cnt    = (int*)(stats + 256);               // 256, zeroed
    char*  zero_end   = (char*)(bin_cnt + 256);
    float* dinv       = (float*)(bin_cnt + 256);           // NN
    int*   row_ptr    = (int*)(dinv + NN);                 // NN+64
    int*   deg8       = row_ptr + NN + 64;                 // NN (padded degree)
    int*   graph_ptr  = deg8 + NN;                         // NG+64
    int*   col_src    = graph_ptr + NG + 64;               // 256*PBCAP (8-aligned rows)
    bf16*  ybuf       = (bf16*)(col_src + 256 * PBCAP);    // (NN+1)*HID, row NN = zeros
    bf16*  outb       = ybuf + (size_t)(NN + 1) * HID;
    char*  wend       = (char*)(outb + (size_t)NN * HID);
    unsigned* bin     = (unsigned*)ybuf;                   // 9.44 MB < ybuf 16.78 MB
    size_t need = (size_t)(wend - base);
    if (ws_size < need) {
        rG_code<<<8, 256, 0, stream>>>(4000.0f + 4.0f * (float)(ws_size >> 20), (float*)d_out);
        return;
    }

    hipMemsetAsync(d_ws, 0, (size_t)(zero_end - base), stream);

    rG_bhist<<<NN / 256, 256, 0, stream>>>(bat, graph_cnt, err);
    rG_bin<<<NE / 8192, 256, 0, stream>>>(ei, bin, bin_cnt, err);
    rG_bscan<<<1, 256, 0, stream>>>(bin_cnt, err);
    rG_scan_graphs<<<1, 1024, 0, stream>>>(graph_cnt, graph_ptr, err);
    rG_sort<<<256, 256, 0, stream>>>(bin, bin_cnt, row_ptr, deg8, dinv, col_src);

    rG_xw1<<<NN / 64, 256, 0, stream>>>(x, W1, dinv, ybuf);
    rG_agg<<<2048, 256, 0, stream>>>(row_ptr, deg8, col_src, dinv, b1, ybuf, outb, stats);
    rG_bnmm<<<NN / 64, 256, 0, stream>>>(outb, stats, g1, be1, W2, dinv, ybuf);
    rG_agg<<<2048, 256, 0, stream>>>(row_ptr, deg8, col_src, dinv, b2, ybuf, outb, stats + 128);
    rG_pool<<<NG, 256, 0, stream>>>(outb, stats + 128, g2, be2, graph_ptr, gf,
                                    Wo1, bo1, Wo2, bo2, Wb1, bb1, Wb2, bb2,
                                    err, (float*)d_out);
}

// Round 4
// 297.738 us; speedup vs baseline: 1.8140x; 1.2081x over previous
//
#include <hip/hip_runtime.h>
#include <hip/hip_bf16.h>

#define NN 131072
#define NE 2097152
#define FIN 32
#define HID 64
#define GFC 16
#define NG 1024
#define EPS 1e-5f
#define BCAP 9216    // per-bucket bin capacity (mean 8192, +11 sigma)
#define PBCAP 12800  // padded bucket capacity: BCAP + 512*7 = 12800 exactly

typedef __hip_bfloat16 bf16;

__device__ __forceinline__ float b2f(bf16 v) { return __bfloat162float(v); }
__device__ __forceinline__ bf16 f2b(float v) { return __float2bfloat16(v); }
__device__ __forceinline__ void rG_err(int* err, int code) { atomicCAS(err, 0, code); }

// accumulate 8 bf16 (as uint4) into acc[8], no mask
__device__ __forceinline__ void rG_add8(float* acc, uint4 a) {
    const unsigned* u = (const unsigned*)&a;
#pragma unroll
    for (int q = 0; q < 4; q++) {
        acc[2 * q]     += __uint_as_float(u[q] << 16);
        acc[2 * q + 1] += __uint_as_float(u[q] & 0xFFFF0000u);
    }
}

// ---------- broadcast diagnostic code (f32 output) ----------
__global__ void rG_code(float code, float* out) {
    int i = blockIdx.x * blockDim.x + threadIdx.x;
    if (i < 2048) out[i] = code;
}

// ---------- batch histogram (batch is sorted -> run-length atomics) ----------
__global__ void rG_bhist(const int* batch, int* graph_cnt, int* err) {
    int n = blockIdx.x * blockDim.x + threadIdx.x;   // grid covers NN exactly
    int lane = threadIdx.x & 63;
    int bg = batch[n];
    if ((unsigned)bg >= NG) { rG_err(err, 3100); bg = 0; }
    int bgp = __shfl_up(bg, 1);
    bool head = (lane == 0) || (bgp != bg);
    int bgn = __shfl_down(bg, 1);
    bool last = (lane == 63) || (bgn != bg);
    unsigned long long hm = __ballot(head);
    if (last) {
        unsigned long long below = (lane == 63) ? hm : (hm & ((1ULL << (lane + 1)) - 1ULL));
        int start = 63 - __clzll(below);
        atomicAdd(&graph_cnt[bg], lane - start + 1);
    }
}

// ---------- bin edges into 256 coarse buckets (dst>>9) ----------
// LDS counting-sort per block, then coalesced run write-out (runs avg 32 x 4B).
__global__ __launch_bounds__(256) void rG_bin(const int* ei, unsigned* bin, int* bin_cnt,
                                              int* err) {
    __shared__ unsigned lsort[8192];
    __shared__ unsigned char bof[8192];
    __shared__ int h[256];
    __shared__ int h2[256];
    __shared__ int lbase[256];
    __shared__ int gbase[256];
    int t = threadIdx.x;
    h[t] = 0;
    h2[t] = 0;
    __syncthreads();
    int start = blockIdx.x * 8192;
    unsigned vals[32];
    unsigned char bks[32];
#pragma unroll
    for (int i = 0; i < 32; i++) {
        int e = start + i * 256 + t;
        int s = ei[e];
        int d = ei[NE + e];
        if ((unsigned)s >= NN || (unsigned)d >= NN) { rG_err(err, 3000); s = 0; d = 0; }
        int b = d >> 9;
        vals[i] = ((unsigned)(d & 511) << 17) | (unsigned)s;
        bks[i] = (unsigned char)b;
        atomicAdd(&h[b], 1);
    }
    __syncthreads();
    // inclusive scan of h into lbase
    lbase[t] = h[t];
    __syncthreads();
    for (int off = 1; off < 256; off <<= 1) {
        int v = (t >= off) ? lbase[t - off] : 0;
        __syncthreads();
        lbase[t] += v;
        __syncthreads();
    }
    gbase[t] = atomicAdd(&bin_cnt[t], h[t]);
    lbase[t] -= h[t];   // exclusive
    __syncthreads();
    // scatter into LDS, sorted by bucket
#pragma unroll
    for (int i = 0; i < 32; i++) {
        int b = bks[i];
        int r = atomicAdd(&h2[b], 1);
        int pos = lbase[b] + r;
        lsort[pos] = vals[i];
        bof[pos] = (unsigned char)b;
    }
    __syncthreads();
    // coalesced copy-out: consecutive i within a run -> consecutive global addrs
    for (int i = t; i < 8192; i += 256) {
        int b = bof[i];
        int p = gbase[b] + (i - lbase[b]);
        if (p >= BCAP) { rG_err(err, 3800); continue; }
        bin[b * BCAP + p] = lsort[i];
    }
}

// ---------- validate bucket totals ----------
__global__ void rG_bscan(const int* bin_cnt, int* err) {
    __shared__ int sh[256];
    int t = threadIdx.x;
    sh[t] = bin_cnt[t];
    __syncthreads();
    for (int off = 128; off > 0; off >>= 1) {
        if (t < off) sh[t] += sh[t + off];
        __syncthreads();
    }
    if (t == 0 && sh[0] != NE) rG_err(err, 2000);
}

// ---------- per-bucket: count 512 locals, 8-pad, scan, scatter in LDS, ------
// ---------- then fully-coalesced col_src write-out ---------------------------
__global__ __launch_bounds__(256) void rG_sort(const unsigned* bin, const int* bin_cnt,
                                               int* row_ptr, int* deg8, float* dinv,
                                               int* col_src) {
    __shared__ int cnt[512];
    __shared__ int sA[512];
    __shared__ int sB[512];
    __shared__ int lout[PBCAP];   // 51.2 KB: padded edge image of this bucket
    int t = threadIdx.x;
    int b = blockIdx.x;
    for (int i = t; i < 512; i += 256) cnt[i] = 0;
    __syncthreads();
    int m = bin_cnt[b];
    if (m > BCAP) m = BCAP;
    // pass 1: count dst-locals (coalesced global read)
    for (int j = t; j < m; j += 256) {
        int dl = bin[b * BCAP + j] >> 17;
        atomicAdd(&cnt[dl], 1);
    }
    __syncthreads();
    // inclusive scan of PADDED counts (multiples of 8)
    for (int i = t; i < 512; i += 256) sA[i] = (cnt[i] + 7) & ~7;
    __syncthreads();
    int* src = sA;
    int* dst = sB;
    for (int off = 1; off < 512; off <<= 1) {
        for (int i = t; i < 512; i += 256)
            dst[i] = src[i] + ((i >= off) ? src[i - off] : 0);
        __syncthreads();
        int* tmp = src; src = dst; dst = tmp;
    }
    // src = inclusive scan of cnt8; dst free for local bases
    int gb = b * PBCAP;
    for (int i = t; i < 512; i += 256) {
        int c = cnt[i];
        int c8 = (c + 7) & ~7;
        int basl = src[i] - c8;             // local base within bucket
        dst[i] = basl;
        row_ptr[b * 512 + i] = gb + basl;
        deg8[b * 512 + i] = c8;
        dinv[b * 512 + i] = rsqrtf((float)c + 1.0f);
    }
    __syncthreads();
    int tot = src[511];                     // total padded edges this bucket
    // pre-fill with sentinel (covers all pad slots), reset cursors
    for (int i = t; i < tot; i += 256) lout[i] = NN;
    for (int i = t; i < 512; i += 256) cnt[i] = 0;
    __syncthreads();
    // pass 2: scatter into LDS (global read is L2-hot second pass)
    for (int j = t; j < m; j += 256) {
        unsigned v = bin[b * BCAP + j];
        int dl = v >> 17;
        int r = atomicAdd(&cnt[dl], 1);
        lout[dst[dl] + r] = (int)(v & 0x1FFFFu);
    }
    __syncthreads();
    // fully coalesced write-out
    for (int i = t; i < tot; i += 256) col_src[gb + i] = lout[i];
}

// ---------- scan graph counts ----------
__global__ void rG_scan_graphs(const int* cnt, int* ptr, int* err) {
    __shared__ int part[1024];
    int t = threadIdx.x;
    int s = cnt[t];
    part[t] = s;
    __syncthreads();
    for (int off = 1; off < 1024; off <<= 1) {
        int v = (t >= off) ? part[t - off] : 0;
        __syncthreads();
        part[t] += v;
        __syncthreads();
    }
    ptr[t] = part[t] - s;
    if (t == 1023) {
        ptr[1024] = part[1023];
        if (part[1023] != NN) rG_err(err, 2500);
    }
}

// ---------- y = (x @ W1) * dinv (bf16 staging); also zeroes sentinel row NN ---
__global__ __launch_bounds__(256) void rG_xw1(const float* x, const float* W1,
                                              const float* dinv, bf16* y) {
    __shared__ float ws[FIN * HID];
    __shared__ float xs[64 * (FIN + 1)];
    int t = threadIdx.x;
    if (blockIdx.x == 0 && t < HID) y[(size_t)NN * HID + t] = f2b(0.f);
    for (int i = t; i < FIN * HID; i += 256) ws[i] = W1[i];
    int nb = blockIdx.x * 64;
    for (int i = t; i < 64 * FIN; i += 256) {
        int n = i / FIN, k = i % FIN;
        xs[n * (FIN + 1) + k] = x[nb * FIN + i];
    }
    __syncthreads();
    int node = t >> 2, fg = t & 3;
    float acc[16];
    for (int j = 0; j < 16; j++) acc[j] = 0.f;
    for (int k = 0; k < FIN; k++) {
        float xv = xs[node * (FIN + 1) + k];
        for (int j = 0; j < 16; j++) acc[j] += xv * ws[k * HID + fg * 16 + j];
    }
    int n = nb + node;
    float dv = dinv[n];
    for (int j = 0; j < 16; j++) y[n * HID + fg * 16 + j] = f2b(acc[j] * dv);
}

// ---------- CSR aggregation: DUAL-STREAM, 16 nodes/wave ----------------------
// lane = ns*8 + c. Two independent 8-node groups (A,B) per wave: both streams'
// gathers (8 each) + index prefetches are issued before either is consumed ->
// ~16-20 outstanding VMEM per lane, 2x the MLP of single-stream. Rows are
// 8-padded with sentinel NN (zero y-row): no masked tails.
__global__ __launch_bounds__(256) void rG_agg(const int* row_ptr, const int* deg8,
                                              const int* col_src,
                                              const float* dinv, const float* bias,
                                              const bf16* y, bf16* outb, float* stats) {
    int t = threadIdx.x;
    int lane = t & 63, wave = t >> 6;
    int ns = lane >> 3;
    int c = lane & 7;
    float bl[8];
#pragma unroll
    for (int k = 0; k < 8; k++) bl[k] = bias[c * 8 + k];
    float ssum[8], ssq[8];
#pragma unroll
    for (int k = 0; k < 8; k++) { ssum[k] = 0.f; ssq[k] = 0.f; }
    int gw = blockIdx.x * 4 + wave;
    int nw = gridDim.x * 4;
    for (int nb = gw * 16; nb < NN; nb += nw * 16) {
        int nA = nb + ns, nB = nb + 8 + ns;
        int eA = row_ptr[nA], eA1 = eA + deg8[nA];
        int eB = row_ptr[nB], eB1 = eB + deg8[nB];
        float accA[8], accB[8];
#pragma unroll
        for (int k = 0; k < 8; k++) { accA[k] = 0.f; accB[k] = 0.f; }
        // self-loop rows: 2 x 1KB coalesced per wave; overlap the idx loads
        uint4 svA = *(const uint4*)(y + (size_t)nA * HID + c * 8);
        uint4 svB = *(const uint4*)(y + (size_t)nB * HID + c * 8);
        uint4 iA0 = {0, 0, 0, 0}, iA1 = iA0, iB0 = iA0, iB1 = iA0;
        if (eA < eA1) {
            iA0 = *(const uint4*)(col_src + eA);
            iA1 = *(const uint4*)(col_src + eA + 4);
        }
        if (eB < eB1) {
            iB0 = *(const uint4*)(col_src + eB);
            iB1 = *(const uint4*)(col_src + eB + 4);
        }
        rG_add8(accA, svA);
        rG_add8(accB, svB);
        while (eA < eA1 || eB < eB1) {
            bool pA = eA < eA1, pB = eB < eB1;
            uint4 fA0 = iA0, fA1 = iA1, fB0 = iB0, fB1 = iB1;
            if (pA && eA + 8 < eA1) {             // prefetch next A indices
                fA0 = *(const uint4*)(col_src + eA + 8);
                fA1 = *(const uint4*)(col_src + eA + 12);
            }
            if (pB && eB + 8 < eB1) {             // prefetch next B indices
                fB0 = *(const uint4*)(col_src + eB + 8);
                fB1 = *(const uint4*)(col_src + eB + 12);
            }
            uint4 gA[8], gB[8];
            if (pA) {
                int ix[8] = {(int)iA0.x, (int)iA0.y, (int)iA0.z, (int)iA0.w,
                             (int)iA1.x, (int)iA1.y, (int)iA1.z, (int)iA1.w};
#pragma unroll
                for (int i = 0; i < 8; i++)
                    gA[i] = *(const uint4*)(y + (size_t)ix[i] * HID + c * 8);
            }
            if (pB) {
                int ix[8] = {(int)iB0.x, (int)iB0.y, (int)iB0.z, (int)iB0.w,
                             (int)iB1.x, (int)iB1.y, (int)iB1.z, (int)iB1.w};
#pragma unroll
                for (int i = 0; i < 8; i++)
                    gB[i] = *(const uint4*)(y + (size_t)ix[i] * HID + c * 8);
            }
            if (pA) {
#pragma unroll
                for (int i = 0; i < 8; i++) rG_add8(accA, gA[i]);
                eA += 8; iA0 = fA0; iA1 = fA1;
            }
            if (pB) {
#pragma unroll
                for (int i = 0; i < 8; i++) rG_add8(accB, gB[i]);
                eB += 8; iB0 = fB0; iB1 = fB1;
            }
        }
        // epilogue A
        {
            float dv = dinv[nA];
            unsigned ob[4];
#pragma unroll
            for (int q = 0; q < 4; q++) {
                float o0 = accA[2 * q] * dv + bl[2 * q];
                float o1 = accA[2 * q + 1] * dv + bl[2 * q + 1];
                ssum[2 * q] += o0; ssq[2 * q] += o0 * o0;
                ssum[2 * q + 1] += o1; ssq[2 * q + 1] += o1 * o1;
                bf16 h0 = f2b(o0), h1 = f2b(o1);
                unsigned short* hp0 = (unsigned short*)&h0;
                unsigned short* hp1 = (unsigned short*)&h1;
                ob[q] = (unsigned)(*hp0) | ((unsigned)(*hp1) << 16);
            }
            *(uint4*)(outb + (size_t)nA * HID + c * 8) = *(uint4*)ob;
        }
        // epilogue B
        {
            float dv = dinv[nB];
            unsigned ob[4];
#pragma unroll
            for (int q = 0; q < 4; q++) {
                float o0 = accB[2 * q] * dv + bl[2 * q];
                float o1 = accB[2 * q + 1] * dv + bl[2 * q + 1];
                ssum[2 * q] += o0; ssq[2 * q] += o0 * o0;
                ssum[2 * q + 1] += o1; ssq[2 * q + 1] += o1 * o1;
                bf16 h0 = f2b(o0), h1 = f2b(o1);
                unsigned short* hp0 = (unsigned short*)&h0;
                unsigned short* hp1 = (unsigned short*)&h1;
                ob[q] = (unsigned)(*hp0) | ((unsigned)(*hp1) << 16);
            }
            *(uint4*)(outb + (size_t)nB * HID + c * 8) = *(uint4*)ob;
        }
    }
    // reduce stats across the 8 node-slot groups (lanes sharing c)
#pragma unroll
    for (int m = 8; m <= 32; m <<= 1) {
#pragma unroll
        for (int k = 0; k < 8; k++) {
            ssum[k] += __shfl_xor(ssum[k], m);
            ssq[k] += __shfl_xor(ssq[k], m);
        }
    }
    __shared__ float ls[64], lq[64];
    if (t < 64) { ls[t] = 0.f; lq[t] = 0.f; }
    __syncthreads();
    if (ns == 0) {
#pragma unroll
        for (int k = 0; k < 8; k++) {
            atomicAdd(&ls[c * 8 + k], ssum[k]);
            atomicAdd(&lq[c * 8 + k], ssq[k]);
        }
    }
    __syncthreads();
    // 8-replica spread: per-address atomic chain 2048 -> 256
    float* sr = stats + (blockIdx.x & 7) * 128;
    if (t < 64) {
        atomicAdd(&sr[t], ls[t]);
        atomicAdd(&sr[64 + t], lq[t]);
    }
}

// ---------- BN1 + ReLU + (h @ W2) * dinv ----------
__global__ __launch_bounds__(256) void rG_bnmm(const bf16* outb, const float* stats,
                                               const float* gamma, const float* beta,
                                               const float* W2, const float* dinv,
                                               bf16* y) {
    __shared__ float w2s[HID * HID];
    __shared__ float hs[64 * (HID + 1)];
    __shared__ float scale[HID], shift[HID];
    int t = threadIdx.x;
    if (t < HID) {
        float s = 0.f, q = 0.f;
#pragma unroll
        for (int r = 0; r < 8; r++) { s += stats[r * 128 + t]; q += stats[r * 128 + 64 + t]; }
        float mu = s * (1.0f / NN);
        float var = q * (1.0f / NN) - mu * mu;
        float rs = rsqrtf(var + EPS);
        float g = gamma[t];
        scale[t] = rs * g;
        shift[t] = beta[t] - mu * rs * g;
    }
    for (int i = t; i < HID * HID; i += 256) w2s[i] = W2[i];
    __syncthreads();
    int nb = blockIdx.x * 64;
    for (int i = t; i < 64 * HID; i += 256) {
        int k = i & 63;
        float v = b2f(outb[(size_t)nb * HID + i]);
        hs[(i >> 6) * (HID + 1) + k] = fmaxf(v * scale[k] + shift[k], 0.f);
    }
    __syncthreads();
    int node = t >> 2, fg = t & 3;
    float acc[16];
    for (int j = 0; j < 16; j++) acc[j] = 0.f;
    for (int k = 0; k < HID; k++) {
        float hv = hs[node * (HID + 1) + k];
        for (int j = 0; j < 16; j++) acc[j] += hv * w2s[k * HID + fg * 16 + j];
    }
    int n = nb + node;
    float dv = dinv[n];
    for (int j = 0; j < 16; j++) y[n * HID + fg * 16 + j] = f2b(acc[j] * dv);
}

// ---------- BN2 + ReLU + mean pool + concat + fused MLP heads ----------------
__global__ __launch_bounds__(256) void rG_pool(const bf16* outb, const float* stats,
                                               const float* gamma, const float* beta,
                                               const int* graph_ptr, const float* gf,
                                               const float* Wo1, const float* bo1,
                                               const float* Wo2, const float* bo2,
                                               const float* Wb1, const float* bb1,
                                               const float* Wb2, const float* bb2,
                                               int* err, float* out) {
    __shared__ float scale[HID], shift[HID];
    __shared__ float red[256];
    __shared__ float cl[80];
    int t = threadIdx.x;
    int g = blockIdx.x;
    if (t < HID) {
        float s = 0.f, q = 0.f;
#pragma unroll
        for (int r = 0; r < 8; r++) { s += stats[r * 128 + t]; q += stats[r * 128 + 64 + t]; }
        float mu = s * (1.0f / NN);
        float var = q * (1.0f / NN) - mu * mu;
        float rs = rsqrtf(var + EPS);
        float ga = gamma[t];
        scale[t] = rs * ga;
        shift[t] = beta[t] - mu * rs * ga;
    }
    __syncthreads();
    int g0 = graph_ptr[g], g1 = graph_ptr[g + 1];
    int f = t & 63, j4 = t >> 6;
    float acc = 0.f;
    for (int n = g0 + j4; n < g1; n += 4)
        acc += fmaxf(b2f(outb[(size_t)n * HID + f]) * scale[f] + shift[f], 0.f);
    red[t] = acc;
    if (t >= 64 && t < 80) cl[t] = gf[g * GFC + (t - 64)];
    __syncthreads();
    if (t < 64) {
        float tot = red[t] + red[64 + t] + red[128 + t] + red[192 + t];
        float c = (float)(g1 - g0);
        cl[t] = tot / fmaxf(c, 1.0f);
    }
    __syncthreads();
    if (t < 64) {
        int j = t & 31, br = t >> 5;
        const float* W1 = br ? Wb1 : Wo1;
        const float* B1 = br ? bb1 : bo1;
        const float* W2 = br ? Wb2 : Wo2;
        const float* B2 = br ? bb2 : bo2;
        float z = B1[j];
#pragma unroll
        for (int k = 0; k < 80; k++) z += cl[k] * W1[k * 32 + j];
        float v = fmaxf(z, 0.f) * W2[j];
#pragma unroll
        for (int m = 1; m < 32; m <<= 1) v += __shfl_xor(v, m);
        if (j == 0) {
            int code = atomicAdd(err, 0);
            out[br * NG + g] = code ? (float)code : (v + B2[0]);
        }
    }
}

extern "C" void kernel_launch(void* const* d_in, const int* in_sizes, int n_in,
                              void* d_out, int out_size, void* d_ws, size_t ws_size,
                              hipStream_t stream) {
    const int expect[20] = {
        NN * FIN, 2 * NE, NN, NG * GFC,
        FIN * HID, HID, HID, HID,
        HID * HID, HID, HID, HID,
        (HID + GFC) * (HID / 2), HID / 2, HID / 2, 1,
        (HID + GFC) * (HID / 2), HID / 2, HID / 2, 1
    };
    if (n_in != 20) {
        rG_code<<<8, 256, 0, stream>>>(9000.0f + (float)n_in, (float*)d_out);
        return;
    }
    for (int i = 0; i < 20; i++) {
        if (in_sizes[i] != expect[i]) {
            rG_code<<<8, 256, 0, stream>>>(8000.0f + 50.0f * (float)i, (float*)d_out);
            return;
        }
    }
    if (out_size != 2048) {
        rG_code<<<8, 256, 0, stream>>>(9900.0f, (float*)d_out);
        return;
    }

    const float* x    = (const float*)d_in[0];
    const int*   ei   = (const int*)d_in[1];
    const int*   bat  = (const int*)d_in[2];
    const float* gf   = (const float*)d_in[3];
    const float* W1   = (const float*)d_in[4];
    const float* b1   = (const float*)d_in[5];
    const float* g1   = (const float*)d_in[6];
    const float* be1  = (const float*)d_in[7];
    const float* W2   = (const float*)d_in[8];
    const float* b2   = (const float*)d_in[9];
    const float* g2   = (const float*)d_in[10];
    const float* be2  = (const float*)d_in[11];
    const float* Wo1  = (const float*)d_in[12];
    const float* bo1  = (const float*)d_in[13];
    const float* Wo2  = (const float*)d_in[14];
    const float* bo2  = (const float*)d_in[15];
    const float* Wb1  = (const float*)d_in[16];
    const float* bb1  = (const float*)d_in[17];
    const float* Wb2  = (const float*)d_in[18];
    const float* bb2  = (const float*)d_in[19];

    char* base = (char*)d_ws;
    int*   err        = (int*)base;                        // 64 ints, zeroed
    int*   graph_cnt  = err + 64;                          // NG, zeroed
    float* stats      = (float*)(graph_cnt + NG);          // 2048 (2 layers x 8 reps x 128), zeroed
    int*   bin_cnt    = (int*)(stats + 2048);              // 256, zeroed
    char*  zero_end   = (char*)(bin_cnt + 256);
    float* dinv       = (float*)(bin_cnt + 256);           // NN
    int*   row_ptr    = (int*)(dinv + NN);                 // NN+64
    int*   deg8       = row_ptr + NN + 64;                 // NN (padded degree)
    int*   graph_ptr  = deg8 + NN;                         // NG+64
    int*   col_src    = graph_ptr + NG + 64;               // 256*PBCAP (8-aligned rows)
    bf16*  ybuf       = (bf16*)(col_src + 256 * PBCAP);    // (NN+1)*HID, row NN = zeros
    bf16*  outb       = ybuf + (size_t)(NN + 1) * HID;
    char*  wend       = (char*)(outb + (size_t)NN * HID);
    unsigned* bin     = (unsigned*)ybuf;                   // 9.44 MB < ybuf 16.78 MB
    size_t need = (size_t)(wend - base);
    if (ws_size < need) {
        rG_code<<<8, 256, 0, stream>>>(4000.0f + 4.0f * (float)(ws_size >> 20), (float*)d_out);
        return;
    }

    hipMemsetAsync(d_ws, 0, (size_t)(zero_end - base), stream);

    rG_bhist<<<NN / 256, 256, 0, stream>>>(bat, graph_cnt, err);
    rG_bin<<<NE / 8192, 256, 0, stream>>>(ei, bin, bin_cnt, err);
    rG_bscan<<<1, 256, 0, stream>>>(bin_cnt, err);
    rG_scan_graphs<<<1, 1024, 0, stream>>>(graph_cnt, graph_ptr, err);
    rG_sort<<<256, 256, 0, stream>>>(bin, bin_cnt, row_ptr, deg8, dinv, col_src);

    rG_xw1<<<NN / 64, 256, 0, stream>>>(x, W1, dinv, ybuf);
    rG_agg<<<2048, 256, 0, stream>>>(row_ptr, deg8, col_src, dinv, b1, ybuf, outb, stats);
    rG_bnmm<<<NN / 64, 256, 0, stream>>>(outb, stats, g1, be1, W2, dinv, ybuf);
    rG_agg<<<2048, 256, 0, stream>>>(row_ptr, deg8, col_src, dinv, b2, ybuf, outb, stats + 1024);
    rG_pool<<<NG, 256, 0, stream>>>(outb, stats + 1024, g2, be2, graph_ptr, gf,
                                    Wo1, bo1, Wo2, bo2, Wb1, bb1, Wb2, bb2,
                                    err, (float*)d_out);
}